// Round 7
// baseline (243.999 us; speedup 1.0000x reference)
//
#include <hip/hip_runtime.h>

#define NXD 128
#define NYD 128
#define SRC_XD 64
#define SRC_YD 64
#define T_STEPSD 256
#define BATCHD 8
#define N_PROBESD 4

typedef float v2f __attribute__((ext_vector_type(2)));

// DPP cross-lane single shifts across the full wave64.
// WAVE_SHR1 (0x138): lane i <- lane i-1, lane0 -> 0 (bound_ctrl)
// WAVE_SHL1 (0x130): lane i <- lane i+1, lane63 -> 0
// Zero-fill matches the conv 'SAME' zero padding at col -1 / col 128.
__device__ __forceinline__ float dpp_from_lower(float v) {
    return __int_as_float(__builtin_amdgcn_update_dpp(0, __float_as_int(v), 0x138, 0xF, 0xF, true));
}
__device__ __forceinline__ float dpp_from_upper(float v) {
    return __int_as_float(__builtin_amdgcn_update_dpp(0, __float_as_int(v), 0x130, 0xF, 0xF, true));
}

// One row update (2 cells). Horizontal cross folded into one packed add:
// cross = {lf, rt} + {Y.y, Y.x}  (swap is a free op_sel on VOP3P).
#define ROW(up, dn, Yr, Zr, Kr) { \
    v2f lr; lr.x = dpp_from_lower((Yr).y); lr.y = dpp_from_upper((Yr).x); \
    v2f ysw; ysw.x = (Yr).y; ysw.y = (Yr).x; \
    const v2f cross = lr + ysw; \
    const v2f lap = ((up) + (dn)) + cross - 4.0f * (Yr); \
    (Zr) = (Kr) * lap + (C2v + K2v * (Zr)); \
}

// Wave-uniform 8-way register select (ro is an SGPR -> scalar branch tree).
#define PSEL(ro, Z, pv) switch (ro) { \
    case 0:  pv = (Z##0);  break; \
    case 1:  pv = (Z##1);  break; \
    case 2:  pv = (Z##2);  break; \
    case 3:  pv = (Z##3);  break; \
    case 4:  pv = (Z##4);  break; \
    case 5:  pv = (Z##5);  break; \
    case 6:  pv = (Z##6);  break; \
    default: pv = (Z##7);  break; \
}

#define PROBES(Z) \
    if (whas0) { v2f pv; PSEL(pro0s, Z, pv) accv0 += pv * pv; } \
    if (whas1) { v2f pv; PSEL(pro1s, Z, pv) accv1 += pv * pv; } \
    if (whas2) { v2f pv; PSEL(pro2s, Z, pv) accv2 += pv * pv; } \
    if (whas3) { v2f pv; PSEL(pro3s, Z, pv) accv3 += pv * pv; }

// Fused 2-step iteration, ONE barrier per 2 steps. 8-row bands, 16 waves.
// Entry: a* = y^t (rows 8w..8w+7), b* = y^{t-1}. LDS buffer p=(t/2)&1 holds
// per band: cur rows R0,R1,R6,R7 and prev rows R0,R7; slot 16 = zero ghost.
// Exit: a* = y^{t+2}, b* = y^{t+1}; edges published into buffer p^1.
#define FSTEP(tt) { \
    const int p_ = ((tt) >> 1) & 1, np_ = p_ ^ 1; \
    const v2f u1 = *(const v2f*)&cB7[p_][wa][colb];   /* y^t[R0-1]    */ \
    const v2f u2 = *(const v2f*)&cB6[p_][wa][colb];   /* y^t[R0-2]    */ \
    v2f pu1      = *(const v2f*)&pB7[p_][wa][colb];   /* y^{t-1}[R0-1]*/ \
    const v2f d1 = *(const v2f*)&cT0[p_][wb][colb];   /* y^t[R7+1]    */ \
    const v2f d2 = *(const v2f*)&cT1[p_][wb][colb];   /* y^t[R7+2]    */ \
    v2f pd1      = *(const v2f*)&pT0[p_][wb][colb];   /* y^{t-1}[R7+1]*/ \
    const float xt0 = xs[tt], xt1 = xs[(tt) + 1]; \
    /* extended halo rows at t+1 (in place over pu1/pd1) */ \
    ROW(u2, a0, u1, pu1, ku) \
    ROW(a7, d2, d1, pd1, kd) \
    if (w == 7) { if (l == (SRC_YD >> 1)) pd1.x += xt0; } /* row 64 = w7's R7+1 */ \
    if (w == 0)  pu1 = zz;   /* ghost row -1 stays 0 (update has const term) */ \
    if (w == 15) pd1 = zz;   /* ghost row 128 */ \
    /* step A: y^{t+1} into b* */ \
    ROW(u1, a1, a0, b0, k0) \
    ROW(a0, a2, a1, b1, k1) \
    ROW(a1, a3, a2, b2, k2) \
    ROW(a2, a4, a3, b3, k3) \
    ROW(a3, a5, a4, b4, k4) \
    ROW(a4, a6, a5, b5, k5) \
    ROW(a5, a7, a6, b6, k6) \
    ROW(a6, d1, a7, b7, k7) \
    if (has_src) { if (own_src) b0.x += xt0; } \
    PROBES(b) \
    /* step B: y^{t+2} into a* */ \
    ROW(pu1, b1,  b0, a0, k0) \
    ROW(b0,  b2,  b1, a1, k1) \
    ROW(b1,  b3,  b2, a2, k2) \
    ROW(b2,  b4,  b3, a3, k3) \
    ROW(b3,  b5,  b4, a4, k4) \
    ROW(b4,  b6,  b5, a5, k5) \
    ROW(b5,  b7,  b6, a6, k6) \
    ROW(b6,  pd1, b7, a7, k7) \
    if (has_src) { if (own_src) a0.x += xt1; } \
    PROBES(a) \
    /* publish new edges into the other buffer, then the ONLY barrier */ \
    *(v2f*)&cT0[np_][w][colb] = a0; \
    *(v2f*)&cT1[np_][w][colb] = a1; \
    *(v2f*)&cB6[np_][w][colb] = a6; \
    *(v2f*)&cB7[np_][w][colb] = a7; \
    *(v2f*)&pT0[np_][w][colb] = b0; \
    *(v2f*)&pB7[np_][w][colb] = b7; \
    __syncthreads(); \
}

// 1024 threads = 16 waves = 4 waves/EU = 1 block/CU. At 4 waves/EU the
// unified budget is 128 regs/wave; state needs only ~85 -> fits in arch
// VGPRs with slack (no AGPR parking). 4 waves/SIMD doubles latency hiding
// vs round 6's 2 -> attacks the ~30% stall component.
__global__ __launch_bounds__(1024)
__attribute__((amdgpu_waves_per_eu(4, 4)))
void wave_sim(
        const float* __restrict__ x,        // (T,B)
        const float* __restrict__ c,        // (NX,NY)
        const int*   __restrict__ probes,   // (4,2) int
        float* __restrict__ partial)        // (B,4)
{
    __shared__ float cT0[2][17][NYD];   // y^t   row R0 per band; [16]=zero ghost
    __shared__ float cT1[2][17][NYD];   // y^t   row R1
    __shared__ float cB6[2][17][NYD];   // y^t   row R6
    __shared__ float cB7[2][17][NYD];   // y^t   row R7
    __shared__ float pT0[2][17][NYD];   // y^{t-1} row R0
    __shared__ float pB7[2][17][NYD];   // y^{t-1} row R7
    __shared__ float xs[T_STEPSD];

    const int tid = threadIdx.x;
    const int w = tid >> 6;       // wave 0..15, owns rows 8w..8w+7
    const int l = tid & 63;       // lane, owns cols 2l, 2l+1
    const int b = blockIdx.x;

    const float dt = 0.5f, bdamp = 0.005f;
    const float denom = 1.0f / (dt * dt) + 0.5f * bdamp / dt;  // 4.005
    const float inv_denom = 1.0f / denom;
    const float C2 = 2.0f * inv_denom;
    const float K2 = (-1.0f - dt * bdamp) * inv_denom;
    const float KL = dt * dt * inv_denom;
    v2f C2v; C2v.x = C2; C2v.y = C2;
    v2f K2v; K2v.x = K2; K2v.y = K2;
    v2f zz; zz.x = 0.0f; zz.y = 0.0f;

    // zero all halo buffers (y^0 = y^{-1} = 0; ghost slots stay 0 forever)
    for (int i = tid; i < 2 * 17 * NYD; i += 1024) {
        ((float*)cT0)[i] = 0.0f; ((float*)cT1)[i] = 0.0f;
        ((float*)cB6)[i] = 0.0f; ((float*)cB7)[i] = 0.0f;
        ((float*)pT0)[i] = 0.0f; ((float*)pB7)[i] = 0.0f;
    }
    if (tid < T_STEPSD) xs[tid] = x[tid * BATCHD + b];

    const int rowbase = w * 8;
    const int colb = 2 * l;
#define LOADK(r) \
    v2f k##r; { \
        const v2f cc = *(const v2f*)&c[(rowbase + r) * NYD + colb]; \
        k##r = KL * cc * cc; \
    }
    LOADK(0) LOADK(1) LOADK(2) LOADK(3) LOADK(4) LOADK(5) LOADK(6) LOADK(7)
#undef LOADK
    // coefficients for the extended halo rows (clamped only to avoid OOB;
    // w==0 / w==15 results are forced to zero anyway)
    const int ru = (rowbase == 0) ? 0 : rowbase - 1;
    const int rd = (rowbase + 8 > 127) ? 127 : rowbase + 8;
    v2f ku, kd;
    { const v2f cc = *(const v2f*)&c[ru * NYD + colb]; ku = KL * cc * cc; }
    { const v2f cc = *(const v2f*)&c[rd * NYD + colb]; kd = KL * cc * cc; }

    v2f a0 = zz, a1 = zz, a2 = zz, a3 = zz, a4 = zz, a5 = zz, a6 = zz, a7 = zz;
    v2f b0 = zz, b1 = zz, b2 = zz, b3 = zz, b4 = zz, b5 = zz, b6 = zz, b7 = zz;

    // probes (wave-uniform coordinates)
    const int px0 = probes[0] & 127, py0 = probes[1] & 127;
    const int px1 = probes[2] & 127, py1 = probes[3] & 127;
    const int px2 = probes[4] & 127, py2 = probes[5] & 127;
    const int px3 = probes[6] & 127, py3 = probes[7] & 127;
    const bool own0 = ((px0 >> 3) == w) && ((py0 >> 1) == l);
    const bool own1 = ((px1 >> 3) == w) && ((py1 >> 1) == l);
    const bool own2 = ((px2 >> 3) == w) && ((py2 >> 1) == l);
    const bool own3 = ((px3 >> 3) == w) && ((py3 >> 1) == l);
    const bool whas0 = __ballot(own0) != 0ULL;
    const bool whas1 = __ballot(own1) != 0ULL;
    const bool whas2 = __ballot(own2) != 0ULL;
    const bool whas3 = __ballot(own3) != 0ULL;
    const int pro0s = __builtin_amdgcn_readfirstlane(px0 & 7);
    const int pro1s = __builtin_amdgcn_readfirstlane(px1 & 7);
    const int pro2s = __builtin_amdgcn_readfirstlane(px2 & 7);
    const int pro3s = __builtin_amdgcn_readfirstlane(px3 & 7);
    const int pel0 = py0 & 1, pel1 = py1 & 1, pel2 = py2 & 1, pel3 = py3 & 1;
    v2f accv0 = zz, accv1 = zz, accv2 = zz, accv3 = zz;

    const bool has_src = (w == (SRC_XD >> 3));            // wave 8 (row 64 = its R0)
    const bool own_src = has_src && (l == (SRC_YD >> 1)); // SRC_YD even -> .x

    const int wa = (w == 0) ? 16 : w - 1;    // 16 = zero ghost slot
    const int wb = (w == 15) ? 16 : w + 1;

    __syncthreads();

#pragma unroll 1
    for (int t = 0; t < T_STEPSD; t += 2) {
        FSTEP(t)
    }

    if (own0) partial[b * N_PROBESD + 0] = pel0 ? accv0.y : accv0.x;
    if (own1) partial[b * N_PROBESD + 1] = pel1 ? accv1.y : accv1.x;
    if (own2) partial[b * N_PROBESD + 2] = pel2 ? accv2.y : accv2.x;
    if (own3) partial[b * N_PROBESD + 3] = pel3 ? accv3.y : accv3.x;
}

__global__ void reduce_k(const float* __restrict__ partial, float* __restrict__ out) {
    const int p = threadIdx.x;
    if (p < N_PROBESD) {
        float s = 0.0f, tot = 0.0f;
        for (int bb = 0; bb < BATCHD; ++bb) s += partial[bb * N_PROBESD + p];
        for (int i = 0; i < BATCHD * N_PROBESD; ++i) tot += partial[i];
        out[p] = s / tot;
    }
}

extern "C" void kernel_launch(void* const* d_in, const int* in_sizes, int n_in,
                              void* d_out, int out_size, void* d_ws, size_t ws_size,
                              hipStream_t stream) {
    const float* x      = (const float*)d_in[0];
    const float* c      = (const float*)d_in[1];
    const int*   probes = (const int*)d_in[2];
    float* out = (float*)d_out;
    float* partial = (float*)d_ws;

    wave_sim<<<BATCHD, 1024, 0, stream>>>(x, c, probes, partial);
    reduce_k<<<1, 64, 0, stream>>>(partial, out);
}